// Round 12
// baseline (132.676 us; speedup 1.0000x reference)
//
#include <hip/hip_runtime.h>
#include <hip/hip_bf16.h>

// MoE fused kernel for MI355X (gfx950) — R12: H-in-LDS, o-partitioned G2.
// out[t,o] = sum_e w[t,e] * (relu(x[t]@W1[e]^T) @ W2[e]^T),
// w = softmax_e(mask( relu(x@sg1^T)@(gate_w@sg_w2)^T + x@gate_w^T ))
//
// 256 blocks (1/CU) x 512 thr (8 waves = wm 0..3 token-groups x wn 0..1).
// Wave (wm,wn): G1 computes H[64 tok][hid half wn] (relu*w folded) into a
// swizzled LDS tile; barrier; G2 computes out[64 tok][out half wn] reading
// ALL hid from LDS. acc2 = [4][4] = 64 regs (o-partitioned) -> total demand
// ~210 regs -> 2 waves/SIMD. Weight RF-ingress 4MB/CU via L1 (~16us), H LDS
// traffic ~3MB (~13us), both under the 33us MFMA floor. 2 fat barriers per
// expert (~5000 cyc matrix-pipe each) amortize drains.
// G1 swapped mfma(W1,X)->D[hid][token] (lane-local token); H stored
// [token][hid] canonical; G2 swapped mfma(W2,H)->D[out][token] -> coalesced
// f32x4 stores. W2 prep-packed in CANONICAL k-order (not R5's perm).
// H swizzle: byte ^= (row&7)<<4 on both write (b64) and read (b128).

typedef float f32x4 __attribute__((ext_vector_type(4)));
typedef short bf16x8 __attribute__((ext_vector_type(8)));

static __device__ __forceinline__ short f2bs(float f) {
  union { __hip_bfloat16 b; short s; } u;
  u.b = __float2bfloat16(f);
  return u.s;
}

static __device__ __forceinline__ unsigned pk2(float lo, float hi) {
  union { __hip_bfloat162 b; unsigned u; } t;
  t.b = __float22bfloat162_rn(make_float2(lo, hi));
  return t.u;
}

// ws layout (shorts):
//  [0,262144)       W1p : (e*64 + ht*4 + kx)*512 + lane*8 + j
//                         = W1[e][ht*16+l15][kx*32+lg*8+j]
//  [262144,524288)  W2p : (e*64 + ot*8 + ks)*512 + lane*8 + j  (CANONICAL)
//                         = W2[e][ot*16+l15][ks*32+lg*8+j]
//  [524288,526336)  sg1p: k*512 + lane*8 + j = sg_w1[l15][k*32+lg*8+j]
//  [526336,528384)  gwp : k*512 + lane*8 + j = l15<8 ? gate_w[l15][...] : 0
//  [528384,528896)  gcp : lane*8 + j = (l15<8 && lg*8+j<16) ? gc[l15][lg*8+j] : 0
//                         gc = gate_w @ sg_w2  [8,16]

__global__ void prep_kernel(const float* __restrict__ sg_w1,
                            const float* __restrict__ sg_w2,
                            const float* __restrict__ gate_w,
                            const float* __restrict__ exp_w1,
                            const float* __restrict__ exp_w2,
                            short* __restrict__ ws_s) {
  int idx = blockIdx.x * 256 + threadIdx.x;
  if (idx < 262144) {
    int e = idx >> 15, rem = idx & 32767;
    int frag = rem >> 9, lane = (rem >> 3) & 63, j = rem & 7;
    int hid = (frag >> 2) * 16 + (lane & 15);
    int k   = (frag & 3) * 32 + (lane >> 4) * 8 + j;
    ws_s[idx] = f2bs(exp_w1[(e * 256 + hid) * 128 + k]);
  } else if (idx < 524288) {
    int i2 = idx - 262144;
    int e = i2 >> 15, rem = i2 & 32767;
    int frag = rem >> 9, lane = (rem >> 3) & 63, j = rem & 7;
    int lg = lane >> 4, l15 = lane & 15;
    int ot = frag >> 3;
    int ks = frag & 7;
    int o  = ot * 16 + l15;
    int h  = ks * 32 + lg * 8 + j;   // canonical k-order
    ws_s[idx] = f2bs(exp_w2[(e * 128 + o) * 256 + h]);
  } else if (idx < 526336) {
    int i3 = idx - 524288;
    int k = i3 >> 9, lane = (i3 >> 3) & 63, j = i3 & 7;
    int lg = lane >> 4, l15 = lane & 15;
    ws_s[idx] = f2bs(sg_w1[l15 * 128 + k * 32 + lg * 8 + j]);
  } else if (idx < 528384) {
    int i4 = idx - 526336;
    int k = i4 >> 9, lane = (i4 >> 3) & 63, j = i4 & 7;
    int lg = lane >> 4, l15 = lane & 15;
    ws_s[idx] = (l15 < 8) ? f2bs(gate_w[l15 * 128 + k * 32 + lg * 8 + j]) : (short)0;
  } else if (idx < 528896) {
    int i5 = idx - 528384;
    int lane = (i5 >> 3) & 63, j = i5 & 7;
    int lg = lane >> 4, l15 = lane & 15;
    int kk = lg * 8 + j;
    if (l15 < 8 && kk < 16) {
      float acc = 0.f;
      for (int d = 0; d < 128; ++d) acc += gate_w[l15 * 128 + d] * sg_w2[d * 16 + kk];
      ws_s[idx] = f2bs(acc);
    } else {
      ws_s[idx] = 0;
    }
  }
}

__global__ __launch_bounds__(512) void moe_kernel(
    const float* __restrict__ x, const int* __restrict__ active,
    const short* __restrict__ ws_s, float* __restrict__ out) {
  // H: 4 token-groups x [64 rows][256 hid] bf16, XOR-swizzled rows. 128KB.
  __shared__ __align__(16) short Hs[65536];

  const short* W1p  = ws_s;
  const short* W2p  = ws_s + 262144;
  const short* sg1p = ws_s + 524288;
  const short* gwp  = ws_s + 526336;
  const short* gcp  = ws_s + 528384;

  const int tid  = threadIdx.x;
  const int lane = tid & 63;
  const int wid  = tid >> 6;     // 0..7
  const int l15  = lane & 15;
  const int lg   = lane >> 4;    // 0..3
  const int wn   = wid & 1;      // hid-half (G1) / out-half (G2)
  const int wm   = wid >> 1;     // token group 0..3
  const int tokw = blockIdx.x * 256 + wm * 64;

  char* Hw = (char*)(Hs + wm * 16384);  // my group's 32KB H tile

  // gate overlay (inside H region, freed after gate): per-wave [64][40] bf16
  short* Ulw = Hs + wid * 2560;
  for (int i = lane; i < 1280; i += 64) ((int*)Ulw)[i] = 0;

  // ---- X fragments: lane holds row=token(l15 + m*16), k=lg*8+j ----
  bf16x8 xf[4][4];
  {
    int trow = tokw + l15;
#pragma unroll
    for (int m = 0; m < 4; ++m) {
      const float* xr = x + (size_t)(trow + m * 16) * 128;
#pragma unroll
      for (int k = 0; k < 4; ++k) {
        int c = k * 32 + lg * 8;
        float4 a = *(const float4*)(xr + c);
        float4 b = *(const float4*)(xr + c + 4);
        bf16x8 v;
        v[0] = f2bs(a.x); v[1] = f2bs(a.y); v[2] = f2bs(a.z); v[3] = f2bs(a.w);
        v[4] = f2bs(b.x); v[5] = f2bs(b.y); v[6] = f2bs(b.z); v[7] = f2bs(b.w);
        xf[m][k] = v;
      }
    }
  }
  __syncthreads();  // zero-init visible before U-writes (cross-lane WAW)

  // ---- gate (verified R6/R11 m=4 structure) ----
  f32x4 wreg[4];
  {
    bf16x8 sgf[4], gwf[4];
#pragma unroll
    for (int k = 0; k < 4; ++k) {
      sgf[k] = *(const bf16x8*)(sg1p + k * 512 + lane * 8);
      gwf[k] = *(const bf16x8*)(gwp  + k * 512 + lane * 8);
    }
#pragma unroll
    for (int m = 0; m < 4; ++m) {
      f32x4 acc = {0.f, 0.f, 0.f, 0.f};
#pragma unroll
      for (int k = 0; k < 4; ++k)
        acc = __builtin_amdgcn_mfma_f32_16x16x32_bf16(xf[m][k], sgf[k], acc, 0, 0, 0);
#pragma unroll
      for (int r = 0; r < 4; ++r)
        Ulw[(m * 16 + lg * 4 + r) * 40 + l15] = f2bs(fmaxf(acc[r], 0.f));
    }
    f32x4 sc[4];
#pragma unroll
    for (int m = 0; m < 4; ++m) {
      f32x4 acc = {0.f, 0.f, 0.f, 0.f};
#pragma unroll
      for (int k = 0; k < 4; ++k)
        acc = __builtin_amdgcn_mfma_f32_16x16x32_bf16(xf[m][k], gwf[k], acc, 0, 0, 0);
      sc[m] = acc;
    }
    __syncthreads();  // U-writes (rows lg*4+r) visible to uf-reads (rows l15)
    bf16x8 gcf = *(const bf16x8*)(gcp + lane * 8);
#pragma unroll
    for (int m = 0; m < 4; ++m) {
      bf16x8 uf = *(const bf16x8*)(Ulw + (m * 16 + l15) * 40 + lg * 8);
      sc[m] = __builtin_amdgcn_mfma_f32_16x16x32_bf16(uf, gcf, sc[m], 0, 0, 0);
    }
    int b = tokw >> 12;
    float am = (l15 < 8 && active[b * 8 + l15] != 0) ? 0.f : -3.0e38f;
#pragma unroll
    for (int m = 0; m < 4; ++m) {
      f32x4 w4;
#pragma unroll
      for (int r = 0; r < 4; ++r) {
        float s = sc[m][r] + am;
        float mx = s;
        mx = fmaxf(mx, __shfl_xor(mx, 1));
        mx = fmaxf(mx, __shfl_xor(mx, 2));
        mx = fmaxf(mx, __shfl_xor(mx, 4));
        float p = __expf(s - mx);
        float su = p;
        su += __shfl_xor(su, 1);
        su += __shfl_xor(su, 2);
        su += __shfl_xor(su, 4);
        w4[r] = p / su;
      }
      wreg[m] = w4;
    }
  }
  __syncthreads();  // gate's U reads done; H region is now free

  // ---- expert loop: G1 -> barrier -> G2 -> barrier ----
  f32x4 acc2[4][4];
#pragma unroll
  for (int m = 0; m < 4; ++m)
#pragma unroll
    for (int o = 0; o < 4; ++o)
      acc2[m][o] = {0.f, 0.f, 0.f, 0.f};

  for (int e = 0; e < 8; ++e) {
    // wv[m] = w[token=l15 (+m*16)][e]; source lane ((l15>>2)<<4)|e, reg l15&3
    float wv[4];
    {
      int srcb = ((l15 >> 2) << 4) | e;
      int rp = l15 & 3;
#pragma unroll
      for (int m = 0; m < 4; ++m) {
        float q0 = __shfl(wreg[m][0], srcb), q1 = __shfl(wreg[m][1], srcb);
        float q2 = __shfl(wreg[m][2], srcb), q3 = __shfl(wreg[m][3], srcb);
        float lo = (rp & 1) ? q1 : q0, hi = (rp & 1) ? q3 : q2;
        wv[m] = (rp & 2) ? hi : lo;
      }
    }

    // ---- G1: H[64 tok][hid half wn] = relu(X@W1^T)*w, written to LDS ----
    const short* w1e = W1p + e * 32768 + lane * 8;
#pragma unroll
    for (int n = 0; n < 8; ++n) {
      int ht = wn * 8 + n;  // global hid tile
      bf16x8 Wf[4];
#pragma unroll
      for (int kx = 0; kx < 4; ++kx)
        Wf[kx] = *(const bf16x8*)(w1e + (ht * 4 + kx) * 512);
#pragma unroll
      for (int m = 0; m < 4; ++m) {
        f32x4 a = {0.f, 0.f, 0.f, 0.f};
#pragma unroll
        for (int kx = 0; kx < 4; ++kx)
          a = __builtin_amdgcn_mfma_f32_16x16x32_bf16(Wf[kx], xf[m][kx], a, 0, 0, 0);
        float s = wv[m];
        uint2 w;
        w.x = pk2(fmaxf(a[0], 0.f) * s, fmaxf(a[1], 0.f) * s);
        w.y = pk2(fmaxf(a[2], 0.f) * s, fmaxf(a[3], 0.f) * s);
        int row = m * 16 + l15;
        int col = wn * 256 + n * 32 + lg * 8;  // byte col in 512B row
        *(uint2*)(Hw + row * 512 + (col ^ ((row & 7) << 4))) = w;
      }
    }
    __syncthreads();  // H complete

    // ---- G2: acc2 += H @ W2^T for out-half wn, K=256 from LDS ----
    const short* w2e = W2p + e * 32768 + lane * 8;
#pragma unroll
    for (int ks = 0; ks < 8; ++ks) {
      bf16x8 hf[4];
#pragma unroll
      for (int m = 0; m < 4; ++m) {
        int row = m * 16 + l15;
        int col = ks * 64 + lg * 16;  // byte col
        hf[m] = *(const bf16x8*)(Hw + row * 512 + (col ^ ((row & 7) << 4)));
      }
#pragma unroll
      for (int o = 0; o < 4; ++o) {
        int ot = wn * 4 + o;
        bf16x8 Bf = *(const bf16x8*)(w2e + (ot * 8 + ks) * 512);
#pragma unroll
        for (int m = 0; m < 4; ++m)
          acc2[m][o] = __builtin_amdgcn_mfma_f32_16x16x32_bf16(Bf, hf[m], acc2[m][o], 0, 0, 0);
      }
    }
    __syncthreads();  // H consumed; next expert may overwrite
  }

  // ---- direct stores: out = wn*64 + o*16 + lg*4..+3, token = l15 (+m*16) ----
#pragma unroll
  for (int m = 0; m < 4; ++m)
#pragma unroll
    for (int o = 0; o < 4; ++o)
      *(f32x4*)(out + (size_t)(tokw + m * 16 + l15) * 128 + wn * 64 + o * 16 + lg * 4) =
          acc2[m][o];

  if (blockIdx.x == 0 && tid == 0) out[8388608] = 0.0f;  // aux_loss
}

extern "C" void kernel_launch(void* const* d_in, const int* in_sizes, int n_in,
                              void* d_out, int out_size, void* d_ws, size_t ws_size,
                              hipStream_t stream) {
  const float* x      = (const float*)d_in[0];
  const int*   act    = (const int*)d_in[1];
  const float* sg_w1  = (const float*)d_in[2];
  const float* sg_w2  = (const float*)d_in[3];
  const float* gate_w = (const float*)d_in[4];
  const float* exp_w1 = (const float*)d_in[5];
  const float* exp_w2 = (const float*)d_in[6];
  short* ws_s = (short*)d_ws;
  float* out = (float*)d_out;

  prep_kernel<<<2066, 256, 0, stream>>>(sg_w1, sg_w2, gate_w, exp_w1, exp_w2, ws_s);
  moe_kernel<<<256, 512, 0, stream>>>(x, act, ws_s, out);
}

// Round 13
// 101.520 us; speedup vs baseline: 1.3069x; 1.3069x over previous
//
#include <hip/hip_runtime.h>
#include <hip/hip_bf16.h>

// MoE fused kernel for MI355X (gfx950) — R13: 64 tok/wave + counted-vmcnt ring.
// out[t,o] = sum_e w[t,e] * (relu(x[t]@W1[e]^T) @ W2[e]^T),
// w = softmax_e(mask( relu(x@sg1^T)@(gate_w@sg_w2)^T + x@gate_w^T ))
//
// 256 blocks (1/CU) x 256 thr (4 waves, 1/SIMD). Each wave owns 64 tokens.
// Weight ingress/CU = 4MB via LDS ring: per 16KB chunk, LDS-pipe ~900cyc
// < 1242cyc MFMA -> matrix pipe is the binding resource for the first time.
// Ring: 4 slots x 16KB, depth-2 prefetch, [stage(c+2)] -> [vmcnt(8)] ->
// [s_barrier] -> [ds_read + compute], NO vmcnt(0) drains (R9-verified).
// 256-thr blocks (not 512) because the compiler caps 512-thr blocks at
// ~128 VGPR and spills (R10/R11); 256-thr reaches 244 (R6).
// Expert math verified R5-R11: G1 swapped mfma(W1,X)->D[hid][token];
// W2 prep-packed (chunk-major, permuted k-order) so relu*w + bf16-pack of
// the G1 accumulator IS a legal G2 B-fragment; G2 swapped -> D[out][token]
// -> direct coalesced f32x4 stores.

typedef float f32x4 __attribute__((ext_vector_type(4)));
typedef short bf16x8 __attribute__((ext_vector_type(8)));

static __device__ __forceinline__ short f2bs(float f) {
  union { __hip_bfloat16 b; short s; } u;
  u.b = __float2bfloat16(f);
  return u.s;
}

static __device__ __forceinline__ unsigned pk2(float lo, float hi) {
  union { __hip_bfloat162 b; unsigned u; } t;
  t.b = __float22bfloat162_rn(make_float2(lo, hi));
  return t.u;
}

// ws layout (shorts):
//  [0,262144)       W1p : (c*8 + i)*512 + lane*8 + j, c=e*8+ks, i=n*4+kx
//                         = W1[e][ks*32+n*16+l15][kx*32+lg*8+j]
//  [262144,524288)  W2p : (c*8 + oi)*512 + lane*8 + j   (chunk-major)
//                         = W2[e][oi*16+l15][ks*32 + perm(lg,j)]
//                           perm(lg,j) = j<4 ? lg*4+j : 16+lg*4+(j-4)
//  [524288,526336)  sg1p: k*512 + lane*8 + j = sg_w1[l15][k*32+lg*8+j]
//  [526336,528384)  gwp : k*512 + lane*8 + j = l15<8 ? gate_w[l15][...] : 0
//  [528384,528896)  gcp : lane*8 + j = (l15<8 && lg*8+j<16) ? gc[l15][lg*8+j] : 0
//                         gc = gate_w @ sg_w2  [8,16]

__global__ void prep_kernel(const float* __restrict__ sg_w1,
                            const float* __restrict__ sg_w2,
                            const float* __restrict__ gate_w,
                            const float* __restrict__ exp_w1,
                            const float* __restrict__ exp_w2,
                            short* __restrict__ ws_s) {
  int idx = blockIdx.x * 256 + threadIdx.x;
  if (idx < 262144) {
    int e = idx >> 15, rem = idx & 32767;
    int frag = rem >> 9, lane = (rem >> 3) & 63, j = rem & 7;
    int hid = (frag >> 2) * 16 + (lane & 15);
    int k   = (frag & 3) * 32 + (lane >> 4) * 8 + j;
    ws_s[idx] = f2bs(exp_w1[(e * 256 + hid) * 128 + k]);
  } else if (idx < 524288) {
    int i2 = idx - 262144;
    int e = i2 >> 15, rem = i2 & 32767;
    int frag = rem >> 9, lane = (rem >> 3) & 63, j = rem & 7;
    int lg = lane >> 4, l15 = lane & 15;
    int ks = frag >> 3;          // chunk-major: frag = ks*8 + oi
    int oi = frag & 7;
    int o  = oi * 16 + l15;
    int h  = ks * 32 + (j < 4 ? lg * 4 + j : 16 + lg * 4 + (j - 4));
    ws_s[idx] = f2bs(exp_w2[(e * 128 + o) * 256 + h]);
  } else if (idx < 526336) {
    int i3 = idx - 524288;
    int k = i3 >> 9, lane = (i3 >> 3) & 63, j = i3 & 7;
    int lg = lane >> 4, l15 = lane & 15;
    ws_s[idx] = f2bs(sg_w1[l15 * 128 + k * 32 + lg * 8 + j]);
  } else if (idx < 528384) {
    int i4 = idx - 526336;
    int k = i4 >> 9, lane = (i4 >> 3) & 63, j = i4 & 7;
    int lg = lane >> 4, l15 = lane & 15;
    ws_s[idx] = (l15 < 8) ? f2bs(gate_w[l15 * 128 + k * 32 + lg * 8 + j]) : (short)0;
  } else if (idx < 528896) {
    int i5 = idx - 528384;
    int lane = (i5 >> 3) & 63, j = i5 & 7;
    int lg = lane >> 4, l15 = lane & 15;
    int kk = lg * 8 + j;
    if (l15 < 8 && kk < 16) {
      float acc = 0.f;
      for (int d = 0; d < 128; ++d) acc += gate_w[l15 * 128 + d] * sg_w2[d * 16 + kk];
      ws_s[idx] = f2bs(acc);
    } else {
      ws_s[idx] = 0;
    }
  }
}

__global__ __launch_bounds__(256, 1) void moe_kernel(
    const float* __restrict__ x, const int* __restrict__ active,
    const short* __restrict__ ws_s, float* __restrict__ out) {
  // 4-deep ring of 16KB weight chunks (slots 0-7 = W1 frags, 8-15 = W2 frags)
  __shared__ __align__(16) short Wring[4][8192];
  __shared__ short Ul[4][2560];  // per-wave [64][40] bf16 U tile (cols 16+ zero)

  const short* W1p  = ws_s;
  const short* W2p  = ws_s + 262144;
  const short* sg1p = ws_s + 524288;
  const short* gwp  = ws_s + 526336;
  const short* gcp  = ws_s + 528384;

  const int tid  = threadIdx.x;
  const int lane = tid & 63;
  const int wid  = tid >> 6;     // 0..3
  const int l15  = lane & 15;
  const int lg   = lane >> 4;    // 0..3
  const int tokw = blockIdx.x * 256 + wid * 64;

  // stage chunk c into ring[c&3]: wave wid copies frags 4*wid..4*wid+3
  // (frag f<8 = W1 frag f; f>=8 = W2 frag f-8). 16B/lane, lane-linear dest.
  auto stage = [&](int c) {
    int buf = c & 3;
#pragma unroll
    for (int t = 0; t < 4; ++t) {
      int f = wid * 4 + t;
      const short* s = (f < 8)
          ? (W1p + ((size_t)c * 8 + f) * 512 + lane * 8)
          : (W2p + ((size_t)c * 8 + (f - 8)) * 512 + lane * 8);
      __builtin_amdgcn_global_load_lds(
          (const __attribute__((address_space(1))) void*)s,
          (__attribute__((address_space(3))) void*)(&Wring[buf][f * 512]),
          16, 0, 0);
    }
  };
  auto waitv = [&](int n) {
    if (n == 8)      asm volatile("s_waitcnt vmcnt(8)" ::: "memory");
    else if (n == 4) asm volatile("s_waitcnt vmcnt(4)" ::: "memory");
    else             asm volatile("s_waitcnt vmcnt(0)" ::: "memory");
    __builtin_amdgcn_sched_barrier(0);
  };

  stage(0);  // depth-2 prologue (drained by gate's syncthreads — fine, once)
  stage(1);

  short* Ulw = &Ul[wid][0];
  for (int i = lane; i < 1280; i += 64) ((int*)Ulw)[i] = 0;

  // ---- X fragments: lane holds row=token(l15 + m*16), k=lg*8+j ----
  bf16x8 xf[4][4];
  {
    int trow = tokw + l15;
#pragma unroll
    for (int m = 0; m < 4; ++m) {
      const float* xr = x + (size_t)(trow + m * 16) * 128;
#pragma unroll
      for (int k = 0; k < 4; ++k) {
        int c = k * 32 + lg * 8;
        float4 a = *(const float4*)(xr + c);
        float4 b = *(const float4*)(xr + c + 4);
        bf16x8 v;
        v[0] = f2bs(a.x); v[1] = f2bs(a.y); v[2] = f2bs(a.z); v[3] = f2bs(a.w);
        v[4] = f2bs(b.x); v[5] = f2bs(b.y); v[6] = f2bs(b.z); v[7] = f2bs(b.w);
        xf[m][k] = v;
      }
    }
  }
  __syncthreads();  // zero-init visible before U-writes (cross-lane WAW)

  // ---- gate (verified R6/R11 m=4 structure) ----
  f32x4 wreg[4];
  {
    bf16x8 sgf[4], gwf[4];
#pragma unroll
    for (int k = 0; k < 4; ++k) {
      sgf[k] = *(const bf16x8*)(sg1p + k * 512 + lane * 8);
      gwf[k] = *(const bf16x8*)(gwp  + k * 512 + lane * 8);
    }
#pragma unroll
    for (int m = 0; m < 4; ++m) {
      f32x4 acc = {0.f, 0.f, 0.f, 0.f};
#pragma unroll
      for (int k = 0; k < 4; ++k)
        acc = __builtin_amdgcn_mfma_f32_16x16x32_bf16(xf[m][k], sgf[k], acc, 0, 0, 0);
#pragma unroll
      for (int r = 0; r < 4; ++r)
        Ulw[(m * 16 + lg * 4 + r) * 40 + l15] = f2bs(fmaxf(acc[r], 0.f));
    }
    f32x4 sc[4];
#pragma unroll
    for (int m = 0; m < 4; ++m) {
      f32x4 acc = {0.f, 0.f, 0.f, 0.f};
#pragma unroll
      for (int k = 0; k < 4; ++k)
        acc = __builtin_amdgcn_mfma_f32_16x16x32_bf16(xf[m][k], gwf[k], acc, 0, 0, 0);
      sc[m] = acc;
    }
    __syncthreads();  // U-writes (rows lg*4+r) visible to uf-reads (rows l15)
    bf16x8 gcf = *(const bf16x8*)(gcp + lane * 8);
#pragma unroll
    for (int m = 0; m < 4; ++m) {
      bf16x8 uf = *(const bf16x8*)(Ulw + (m * 16 + l15) * 40 + lg * 8);
      sc[m] = __builtin_amdgcn_mfma_f32_16x16x32_bf16(uf, gcf, sc[m], 0, 0, 0);
    }
    int b = tokw >> 12;
    float am = (l15 < 8 && active[b * 8 + l15] != 0) ? 0.f : -3.0e38f;
#pragma unroll
    for (int m = 0; m < 4; ++m) {
      f32x4 w4;
#pragma unroll
      for (int r = 0; r < 4; ++r) {
        float s = sc[m][r] + am;
        float mx = s;
        mx = fmaxf(mx, __shfl_xor(mx, 1));
        mx = fmaxf(mx, __shfl_xor(mx, 2));
        mx = fmaxf(mx, __shfl_xor(mx, 4));
        float p = __expf(s - mx);
        float su = p;
        su += __shfl_xor(su, 1);
        su += __shfl_xor(su, 2);
        su += __shfl_xor(su, 4);
        w4[r] = p / su;
      }
      wreg[m] = w4;
    }
  }

  // ---- expert loop: counted-vmcnt ring pipeline, no drains ----
  f32x4 acc2[4][8];
#pragma unroll
  for (int m = 0; m < 4; ++m)
#pragma unroll
    for (int o = 0; o < 8; ++o)
      acc2[m][o] = {0.f, 0.f, 0.f, 0.f};

  for (int e = 0; e < 8; ++e) {
    // wv[m] = w[token=l15 (+m*16)][e]; source lane ((l15>>2)<<4)|e, reg l15&3
    float wv[4];
    {
      int srcb = ((l15 >> 2) << 4) | e;
      int rp = l15 & 3;
#pragma unroll
      for (int m = 0; m < 4; ++m) {
        float q0 = __shfl(wreg[m][0], srcb), q1 = __shfl(wreg[m][1], srcb);
        float q2 = __shfl(wreg[m][2], srcb), q3 = __shfl(wreg[m][3], srcb);
        float lo = (rp & 1) ? q1 : q0, hi = (rp & 1) ? q3 : q2;
        wv[m] = (rp & 2) ? hi : lo;
      }
    }

#pragma unroll 1
    for (int ks = 0; ks < 8; ++ks) {
      const int c = e * 8 + ks;
      if (c + 2 < 64) stage(c + 2);           // issue prefetch (never drained)
      waitv(c <= 61 ? 8 : (c == 62 ? 4 : 0)); // own chunk-c loads have landed
      __builtin_amdgcn_s_barrier();           // everyone's chunk-c loads landed

      const short* rb = &Wring[c & 3][0];
      __builtin_amdgcn_s_setprio(1);

      // G1 + immediate pack (Af 4-at-a-time; static hu indexing)
      union HU { unsigned u[4]; bf16x8 v; };
      HU hu[4];
#pragma unroll
      for (int n = 0; n < 2; ++n) {
        bf16x8 Af[4];
#pragma unroll
        for (int kx = 0; kx < 4; ++kx)
          Af[kx] = *(const bf16x8*)(rb + (n * 4 + kx) * 512 + lane * 8);
#pragma unroll
        for (int m = 0; m < 4; ++m) {
          f32x4 a = {0.f, 0.f, 0.f, 0.f};
#pragma unroll
          for (int kx = 0; kx < 4; ++kx)
            a = __builtin_amdgcn_mfma_f32_16x16x32_bf16(Af[kx], xf[m][kx], a, 0, 0, 0);
          float s = wv[m];
          hu[m].u[n * 2]     = pk2(fmaxf(a[0], 0.f) * s, fmaxf(a[1], 0.f) * s);
          hu[m].u[n * 2 + 1] = pk2(fmaxf(a[2], 0.f) * s, fmaxf(a[3], 0.f) * s);
        }
      }
      // G2: acc2[m][o] += mfma(W2frag[o], hB[m])  (D[out][token])
#pragma unroll
      for (int o = 0; o < 8; ++o) {
        bf16x8 Bf = *(const bf16x8*)(rb + 4096 + o * 512 + lane * 8);
#pragma unroll
        for (int m = 0; m < 4; ++m)
          acc2[m][o] = __builtin_amdgcn_mfma_f32_16x16x32_bf16(Bf, hu[m].v, acc2[m][o], 0, 0, 0);
      }
      __builtin_amdgcn_s_setprio(0);
    }
  }

  // ---- direct stores: lane holds out = o*16+lg*4..+3, token = l15 (+m*16) ----
#pragma unroll
  for (int m = 0; m < 4; ++m)
#pragma unroll
    for (int o = 0; o < 8; ++o)
      *(f32x4*)(out + (size_t)(tokw + m * 16 + l15) * 128 + o * 16 + lg * 4) = acc2[m][o];

  if (blockIdx.x == 0 && tid == 0) out[8388608] = 0.0f;  // aux_loss
}

extern "C" void kernel_launch(void* const* d_in, const int* in_sizes, int n_in,
                              void* d_out, int out_size, void* d_ws, size_t ws_size,
                              hipStream_t stream) {
  const float* x      = (const float*)d_in[0];
  const int*   act    = (const int*)d_in[1];
  const float* sg_w1  = (const float*)d_in[2];
  const float* sg_w2  = (const float*)d_in[3];
  const float* gate_w = (const float*)d_in[4];
  const float* exp_w1 = (const float*)d_in[5];
  const float* exp_w2 = (const float*)d_in[6];
  short* ws_s = (short*)d_ws;
  float* out = (float*)d_out;

  prep_kernel<<<2066, 256, 0, stream>>>(sg_w1, sg_w2, gate_w, exp_w1, exp_w2, ws_s);
  moe_kernel<<<256, 256, 0, stream>>>(x, act, ws_s, out);
}

// Round 14
// 85.242 us; speedup vs baseline: 1.5565x; 1.1910x over previous
//
#include <hip/hip_runtime.h>
#include <hip/hip_bf16.h>

// MoE fused kernel for MI355X (gfx950) — R14: expert-split on 256-thr blocks.
// out[t,o] = sum_e w[t,e] * (relu(x[t]@W1[e]^T) @ W2[e]^T),
// w = softmax_e(mask( relu(x@sg1^T)@(gate_w@sg_w2)^T + x@gate_w^T ))
//
// 512 blocks x 256 thr (4 waves = lw{0,1} token-groups x hf{0,1} expert
// halves), 2 blocks/CU -> 8 waves/CU, 2 waves/SIMD (MFMA||VALU co-issue).
// Each wave: 64 tokens x 4 experts -> 0.5MB weights -> 4MB/CU LDS ingress
// (~20us) < 33us MFMA floor. Ring: 2 slots x 32KB (both halves), depth-1
// prefetch, per phase: [vmcnt(0) of own 8 loads issued a full phase ago]
// -> [s_barrier] -> [stage(p+1)] -> [compute]  (R10-verified order).
// Halves combined via R10's verified 2-round [16][132] LDS epilogue.
// 256-thr blocks because 512-thr blocks are VGPR-capped ~128 (R10/R11
// spill); (256,2) allows ~256.
// Expert math verified R5-R13: G1 swapped mfma(W1,X)->D[hid][token];
// W2 prep-packed (chunk-major, permuted k-order) so relu*w + bf16-pack of
// the G1 accumulator IS a legal G2 B-fragment; G2 swapped -> D[out][token].

typedef float f32x4 __attribute__((ext_vector_type(4)));
typedef short bf16x8 __attribute__((ext_vector_type(8)));

static __device__ __forceinline__ short f2bs(float f) {
  union { __hip_bfloat16 b; short s; } u;
  u.b = __float2bfloat16(f);
  return u.s;
}

static __device__ __forceinline__ unsigned pk2(float lo, float hi) {
  union { __hip_bfloat162 b; unsigned u; } t;
  t.b = __float22bfloat162_rn(make_float2(lo, hi));
  return t.u;
}

// ws layout (shorts):
//  [0,262144)       W1p : (c*8 + i)*512 + lane*8 + j, c=e*8+ks, i=n*4+kx
//                         = W1[e][ks*32+n*16+l15][kx*32+lg*8+j]
//  [262144,524288)  W2p : (c*8 + oi)*512 + lane*8 + j   (chunk-major)
//                         = W2[e][oi*16+l15][ks*32 + perm(lg,j)]
//                           perm(lg,j) = j<4 ? lg*4+j : 16+lg*4+(j-4)
//  [524288,526336)  sg1p: k*512 + lane*8 + j = sg_w1[l15][k*32+lg*8+j]
//  [526336,528384)  gwp : k*512 + lane*8 + j = l15<8 ? gate_w[l15][...] : 0
//  [528384,528896)  gcp : lane*8 + j = (l15<8 && lg*8+j<16) ? gc[l15][lg*8+j] : 0
//                         gc = gate_w @ sg_w2  [8,16]

__global__ void prep_kernel(const float* __restrict__ sg_w1,
                            const float* __restrict__ sg_w2,
                            const float* __restrict__ gate_w,
                            const float* __restrict__ exp_w1,
                            const float* __restrict__ exp_w2,
                            short* __restrict__ ws_s) {
  int idx = blockIdx.x * 256 + threadIdx.x;
  if (idx < 262144) {
    int e = idx >> 15, rem = idx & 32767;
    int frag = rem >> 9, lane = (rem >> 3) & 63, j = rem & 7;
    int hid = (frag >> 2) * 16 + (lane & 15);
    int k   = (frag & 3) * 32 + (lane >> 4) * 8 + j;
    ws_s[idx] = f2bs(exp_w1[(e * 256 + hid) * 128 + k]);
  } else if (idx < 524288) {
    int i2 = idx - 262144;
    int e = i2 >> 15, rem = i2 & 32767;
    int frag = rem >> 9, lane = (rem >> 3) & 63, j = rem & 7;
    int lg = lane >> 4, l15 = lane & 15;
    int ks = frag >> 3;          // chunk-major: frag = ks*8 + oi
    int oi = frag & 7;
    int o  = oi * 16 + l15;
    int h  = ks * 32 + (j < 4 ? lg * 4 + j : 16 + lg * 4 + (j - 4));
    ws_s[idx] = f2bs(exp_w2[(e * 128 + o) * 256 + h]);
  } else if (idx < 526336) {
    int i3 = idx - 524288;
    int k = i3 >> 9, lane = (i3 >> 3) & 63, j = i3 & 7;
    int lg = lane >> 4, l15 = lane & 15;
    ws_s[idx] = f2bs(sg_w1[l15 * 128 + k * 32 + lg * 8 + j]);
  } else if (idx < 528384) {
    int i4 = idx - 526336;
    int k = i4 >> 9, lane = (i4 >> 3) & 63, j = i4 & 7;
    int lg = lane >> 4, l15 = lane & 15;
    ws_s[idx] = (l15 < 8) ? f2bs(gate_w[l15 * 128 + k * 32 + lg * 8 + j]) : (short)0;
  } else if (idx < 528896) {
    int i5 = idx - 528384;
    int lane = (i5 >> 3) & 63, j = i5 & 7;
    int lg = lane >> 4, l15 = lane & 15;
    int kk = lg * 8 + j;
    if (l15 < 8 && kk < 16) {
      float acc = 0.f;
      for (int d = 0; d < 128; ++d) acc += gate_w[l15 * 128 + d] * sg_w2[d * 16 + kk];
      ws_s[idx] = f2bs(acc);
    } else {
      ws_s[idx] = 0;
    }
  }
}

__global__ __launch_bounds__(256, 2) void moe_kernel(
    const float* __restrict__ x, const int* __restrict__ active,
    const short* __restrict__ ws_s, float* __restrict__ out) {
  // 2-slot ring: slot = [2 halves][16 frags][512 shorts] = 32KB; total 64KB.
  // Gate-U tiles ([64][40] bf16/wave = 10KB total) overlay slot 0.
  __shared__ __align__(16) short ringS[2][16384];

  const short* W1p  = ws_s;
  const short* W2p  = ws_s + 262144;
  const short* sg1p = ws_s + 524288;
  const short* gwp  = ws_s + 526336;
  const short* gcp  = ws_s + 528384;

  const int tid  = threadIdx.x;
  const int lane = tid & 63;
  const int wid  = tid >> 6;     // 0..3
  const int l15  = lane & 15;
  const int lg   = lane >> 4;    // 0..3
  const int lw   = wid & 1;      // token group
  const int hf   = wid >> 1;     // expert half
  const int eb   = hf * 4;       // expert base
  const int tokw = blockIdx.x * 128 + lw * 64;

  // stage phase p for MY half into ring[p&1]; the 2 waves of half hf each
  // stage 8 frags (f = lw*8+t). f<8 = W1 frag f, f>=8 = W2 frag f-8.
  auto stage = [&](int p) {
    int cq = (eb + (p >> 3)) * 8 + (p & 7);
    short* db = &ringS[p & 1][hf * 8192];
#pragma unroll
    for (int t = 0; t < 8; ++t) {
      int f = lw * 8 + t;
      const short* s = (f < 8)
          ? (W1p + ((size_t)cq * 8 + f) * 512 + lane * 8)
          : (W2p + ((size_t)cq * 8 + (f - 8)) * 512 + lane * 8);
      __builtin_amdgcn_global_load_lds(
          (const __attribute__((address_space(1))) void*)s,
          (__attribute__((address_space(3))) void*)(&db[f * 512]),
          16, 0, 0);
    }
  };

  short* Ulw = &ringS[0][0] + wid * 2560;  // per-wave [64][40] bf16 U tile
  for (int i = lane; i < 1280; i += 64) ((int*)Ulw)[i] = 0;

  // ---- X fragments: lane holds row=token(l15 + m*16), k=lg*8+j ----
  bf16x8 xf[4][4];
  {
    int trow = tokw + l15;
#pragma unroll
    for (int m = 0; m < 4; ++m) {
      const float* xr = x + (size_t)(trow + m * 16) * 128;
#pragma unroll
      for (int k = 0; k < 4; ++k) {
        int c = k * 32 + lg * 8;
        float4 a = *(const float4*)(xr + c);
        float4 b = *(const float4*)(xr + c + 4);
        bf16x8 v;
        v[0] = f2bs(a.x); v[1] = f2bs(a.y); v[2] = f2bs(a.z); v[3] = f2bs(a.w);
        v[4] = f2bs(b.x); v[5] = f2bs(b.y); v[6] = f2bs(b.z); v[7] = f2bs(b.w);
        xf[m][k] = v;
      }
    }
  }
  __syncthreads();  // zero-init visible before U-writes (cross-lane WAW)

  // ---- gate (verified R6/R11/R13 m=4 structure) ----
  float wv4[4][4];  // [my 4 experts][m]
  {
    f32x4 wreg[4];
    bf16x8 sgf[4], gwf[4];
#pragma unroll
    for (int k = 0; k < 4; ++k) {
      sgf[k] = *(const bf16x8*)(sg1p + k * 512 + lane * 8);
      gwf[k] = *(const bf16x8*)(gwp  + k * 512 + lane * 8);
    }
#pragma unroll
    for (int m = 0; m < 4; ++m) {
      f32x4 acc = {0.f, 0.f, 0.f, 0.f};
#pragma unroll
      for (int k = 0; k < 4; ++k)
        acc = __builtin_amdgcn_mfma_f32_16x16x32_bf16(xf[m][k], sgf[k], acc, 0, 0, 0);
#pragma unroll
      for (int r = 0; r < 4; ++r)
        Ulw[(m * 16 + lg * 4 + r) * 40 + l15] = f2bs(fmaxf(acc[r], 0.f));
    }
    f32x4 sc[4];
#pragma unroll
    for (int m = 0; m < 4; ++m) {
      f32x4 acc = {0.f, 0.f, 0.f, 0.f};
#pragma unroll
      for (int k = 0; k < 4; ++k)
        acc = __builtin_amdgcn_mfma_f32_16x16x32_bf16(xf[m][k], gwf[k], acc, 0, 0, 0);
      sc[m] = acc;
    }
    __syncthreads();  // U-writes (rows lg*4+r) visible to uf-reads (rows l15)
    bf16x8 gcf = *(const bf16x8*)(gcp + lane * 8);
#pragma unroll
    for (int m = 0; m < 4; ++m) {
      bf16x8 uf = *(const bf16x8*)(Ulw + (m * 16 + l15) * 40 + lg * 8);
      sc[m] = __builtin_amdgcn_mfma_f32_16x16x32_bf16(uf, gcf, sc[m], 0, 0, 0);
    }
    int b = tokw >> 12;
    float am = (l15 < 8 && active[b * 8 + l15] != 0) ? 0.f : -3.0e38f;
#pragma unroll
    for (int m = 0; m < 4; ++m) {
      f32x4 w4;
#pragma unroll
      for (int r = 0; r < 4; ++r) {
        float s = sc[m][r] + am;
        float mx = s;
        mx = fmaxf(mx, __shfl_xor(mx, 1));
        mx = fmaxf(mx, __shfl_xor(mx, 2));
        mx = fmaxf(mx, __shfl_xor(mx, 4));
        float p = __expf(s - mx);
        float su = p;
        su += __shfl_xor(su, 1);
        su += __shfl_xor(su, 2);
        su += __shfl_xor(su, 4);
        w4[r] = p / su;
      }
      wreg[m] = w4;
    }
    // extract my half's gate weights (R11-verified): wv4[e4][m]
#pragma unroll
    for (int e4 = 0; e4 < 4; ++e4) {
      int srcb = ((l15 >> 2) << 4) | (eb + e4);
      int rp = l15 & 3;
#pragma unroll
      for (int m = 0; m < 4; ++m) {
        float q0 = __shfl(wreg[m][0], srcb), q1 = __shfl(wreg[m][1], srcb);
        float q2 = __shfl(wreg[m][2], srcb), q3 = __shfl(wreg[m][3], srcb);
        float lo = (rp & 1) ? q1 : q0, hi = (rp & 1) ? q3 : q2;
        wv4[e4][m] = (rp & 2) ? hi : lo;
      }
    }
  }
  __syncthreads();  // gate's U reads done; ring slot 0 free for staging

  stage(0);  // depth-1 prologue

  // ---- expert loop: 32 phases, vmcnt(0)-of-own-prefetch + s_barrier ----
  f32x4 acc2[4][8];
#pragma unroll
  for (int m = 0; m < 4; ++m)
#pragma unroll
    for (int o = 0; o < 8; ++o)
      acc2[m][o] = {0.f, 0.f, 0.f, 0.f};

#pragma unroll 1
  for (int p = 0; p < 32; ++p) {
    const int e4 = p >> 3;
    asm volatile("s_waitcnt vmcnt(0)" ::: "memory");  // own stage(p) landed
    __builtin_amdgcn_sched_barrier(0);
    __builtin_amdgcn_s_barrier();                     // everyone's landed
    __builtin_amdgcn_sched_barrier(0);
    if (p + 1 < 32) stage(p + 1);  // WAR-safe: all waves passed barrier(p)

    const short* rb = &ringS[p & 1][hf * 8192];
    __builtin_amdgcn_s_setprio(1);

    // G1 + immediate pack (Af 4-at-a-time; static hu indexing) — R13 body
    union HU { unsigned u[4]; bf16x8 v; };
    HU hu[4];
#pragma unroll
    for (int n = 0; n < 2; ++n) {
      bf16x8 Af[4];
#pragma unroll
      for (int kx = 0; kx < 4; ++kx)
        Af[kx] = *(const bf16x8*)(rb + (n * 4 + kx) * 512 + lane * 8);
#pragma unroll
      for (int m = 0; m < 4; ++m) {
        f32x4 a = {0.f, 0.f, 0.f, 0.f};
#pragma unroll
        for (int kx = 0; kx < 4; ++kx)
          a = __builtin_amdgcn_mfma_f32_16x16x32_bf16(Af[kx], xf[m][kx], a, 0, 0, 0);
        float s = wv4[e4][m];
        hu[m].u[n * 2]     = pk2(fmaxf(a[0], 0.f) * s, fmaxf(a[1], 0.f) * s);
        hu[m].u[n * 2 + 1] = pk2(fmaxf(a[2], 0.f) * s, fmaxf(a[3], 0.f) * s);
      }
    }
    // G2: acc2[m][o] += mfma(W2frag[o], hB[m])  (D[out][token])
#pragma unroll
    for (int o = 0; o < 8; ++o) {
      bf16x8 Bf = *(const bf16x8*)(rb + 4096 + o * 512 + lane * 8);
#pragma unroll
      for (int m = 0; m < 4; ++m)
        acc2[m][o] = __builtin_amdgcn_mfma_f32_16x16x32_bf16(Bf, hu[m].v, acc2[m][o], 0, 0, 0);
    }
    __builtin_amdgcn_s_setprio(0);
  }

  // ---- epilogue: combine halves via LDS (R10-verified 2-round pattern) ----
  __syncthreads();
  float* ep = (float*)&ringS[0][0];  // regions (lw*2+mm)*2112 floats, [16][132]
#pragma unroll
  for (int rr = 0; rr < 2; ++rr) {
    if (hf == 1) {
#pragma unroll
      for (int mm = 0; mm < 2; ++mm) {
#pragma unroll
        for (int o = 0; o < 8; ++o)
          *(f32x4*)&ep[(lw * 2 + mm) * 2112 + l15 * 132 + o * 16 + lg * 4] =
              acc2[rr * 2 + mm][o];
      }
    }
    __syncthreads();
    if (hf == 0) {
#pragma unroll
      for (int mm = 0; mm < 2; ++mm) {
#pragma unroll
        for (int o = 0; o < 8; ++o) {
          f32x4 v = *(const f32x4*)&ep[(lw * 2 + mm) * 2112 + l15 * 132 + o * 16 + lg * 4];
          f32x4 r = acc2[rr * 2 + mm][o];
          r[0] += v[0]; r[1] += v[1]; r[2] += v[2]; r[3] += v[3];
          *(f32x4*)(out + (size_t)(tokw + (rr * 2 + mm) * 16 + l15) * 128 + o * 16 + lg * 4) = r;
        }
      }
    }
    __syncthreads();
  }
  if (blockIdx.x == 0 && tid == 0) out[8388608] = 0.0f;  // aux_loss
}

extern "C" void kernel_launch(void* const* d_in, const int* in_sizes, int n_in,
                              void* d_out, int out_size, void* d_ws, size_t ws_size,
                              hipStream_t stream) {
  const float* x      = (const float*)d_in[0];
  const int*   act    = (const int*)d_in[1];
  const float* sg_w1  = (const float*)d_in[2];
  const float* sg_w2  = (const float*)d_in[3];
  const float* gate_w = (const float*)d_in[4];
  const float* exp_w1 = (const float*)d_in[5];
  const float* exp_w2 = (const float*)d_in[6];
  short* ws_s = (short*)d_ws;
  float* out = (float*)d_out;

  prep_kernel<<<2066, 256, 0, stream>>>(sg_w1, sg_w2, gate_w, exp_w1, exp_w2, ws_s);
  moe_kernel<<<512, 256, 0, stream>>>(x, act, ws_s, out);
}